// Round 1
// baseline (183.940 us; speedup 1.0000x reference)
//
#include <hip/hip_runtime.h>
#include <hip/hip_bf16.h>

typedef __attribute__((ext_vector_type(4))) float f32x4;
typedef __attribute__((ext_vector_type(8))) short bf16x8;

static __device__ __forceinline__ unsigned int pack_bf16_pair(float a, float b) {
  union { __hip_bfloat16 h; unsigned short u; } ca, cb;
  ca.h = __float2bfloat16(a);
  cb.h = __float2bfloat16(b);
  return (unsigned int)ca.u | ((unsigned int)cb.u << 16);
}

// ---------------------------------------------------------------------------
// Projection: x[32768 rows][64] -> g (row-major f32), f^T (f32), h^T (bf16)
// One block = 64 rows. LDS-staged x tile + all three kernel matrices.
// Thread (r = t>>2, u = t&3) computes 20 contiguous outputs o = u*20..u*20+19
// of the packed [f(8) | g(8) | h(64)] output vector for row r.
// ---------------------------------------------------------------------------
__global__ __launch_bounds__(256) void proj_kernel(
    const float* __restrict__ x, const float* __restrict__ kf,
    const float* __restrict__ kg, const float* __restrict__ kh,
    float* __restrict__ g_g, float* __restrict__ ft_g,
    unsigned short* __restrict__ ht_g)
{
  __shared__ float xs[64*68];   // +4 pad: 16B-aligned rows, 2-way max on col reads
  __shared__ float ks[64*80];   // [c][o]: o = f(0..7) g(8..15) h(16..79)
  const int t = threadIdx.x;
  const long R0 = (long)blockIdx.x * 64;

  {
    const float4* xp = (const float4*)(x + R0*64);
    #pragma unroll
    for (int p = 0; p < 4; ++p) {
      int e4 = t + p*256;
      float4 v = xp[e4];
      int e = e4*4;
      int r = e >> 6, c = e & 63;
      *(float4*)&xs[r*68 + c] = v;
    }
  }
  if (t < 128) {
    float4 v = ((const float4*)kf)[t];
    int e = t*4; int c = e >> 3, o = e & 7;
    *(float4*)&ks[c*80 + o] = v;
  } else {
    int t2 = t - 128;
    float4 v = ((const float4*)kg)[t2];
    int e = t2*4; int c = e >> 3, o = e & 7;
    *(float4*)&ks[c*80 + 8 + o] = v;
  }
  #pragma unroll
  for (int p = 0; p < 4; ++p) {
    int e4 = t + p*256;
    float4 v = ((const float4*)kh)[e4];
    int e = e4*4; int c = e >> 6, o = e & 63;
    *(float4*)&ks[c*80 + 16 + o] = v;
  }
  __syncthreads();

  const int r = t >> 2, u = t & 3;
  float acc[20];
  #pragma unroll
  for (int k = 0; k < 20; ++k) acc[k] = 0.f;
  #pragma unroll 4
  for (int c = 0; c < 64; ++c) {
    float xv = xs[r*68 + c];
    const float* kp = &ks[c*80 + u*20];
    #pragma unroll
    for (int k5 = 0; k5 < 5; ++k5) {
      float4 kv = *(const float4*)&kp[k5*4];
      acc[k5*4+0] = fmaf(xv, kv.x, acc[k5*4+0]);
      acc[k5*4+1] = fmaf(xv, kv.y, acc[k5*4+1]);
      acc[k5*4+2] = fmaf(xv, kv.z, acc[k5*4+2]);
      acc[k5*4+3] = fmaf(xv, kv.w, acc[k5*4+3]);
    }
  }
  const long Rg = R0 + r;
  const int b = (int)(Rg >> 12);
  const int n = (int)(Rg & 4095);
  if (u == 0) {
    #pragma unroll
    for (int d = 0; d < 8; ++d)
      ft_g[((long)b*8 + d)*4096 + n] = acc[d];        // f transposed
    #pragma unroll
    for (int d = 0; d < 8; ++d)
      g_g[Rg*8 + d] = acc[8+d];                       // g row-major
    #pragma unroll
    for (int cc = 0; cc < 4; ++cc) {
      union { __hip_bfloat16 h; unsigned short us; } cv;
      cv.h = __float2bfloat16(acc[16+cc]);
      ht_g[((long)b*64 + cc)*4096 + n] = cv.us;       // h transposed, bf16
    }
  } else {
    const int c0 = u*20 - 16;
    #pragma unroll
    for (int k = 0; k < 20; ++k) {
      union { __hip_bfloat16 h; unsigned short us; } cv;
      cv.h = __float2bfloat16(acc[k]);
      ht_g[((long)b*64 + (c0+k))*4096 + n] = cv.us;
    }
  }
}

// ---------------------------------------------------------------------------
// Flash attention: block = (64 queries) x (batch). Key tiles of 128, 32 iters.
// Phase A (VALU fp32): thread (sq=t>>2, skg=t&3) computes 32 scores for keys
//   k = ig*32 + skg*8 + j  (8-granular interleave -> ft bank groups {0,8,16,24})
//   online softmax via quad shfl_xor(1,2); p packed bf16 pairs -> pb[64][65].
// Phase B (MFMA): wave w owns O rows 16w..16w+15 (C-layout), A-frags read
//   wave-locally from pb, B-frags are contiguous ds_read_b128 from h^T tile.
// ---------------------------------------------------------------------------
__global__ __launch_bounds__(256) void attn_kernel(
    const float* __restrict__ x, const float* __restrict__ g_g,
    const float* __restrict__ ft_g, const unsigned short* __restrict__ ht_g,
    const float* __restrict__ gamma_p, float* __restrict__ out)
{
  __shared__ float fts[8*128];            // f^T tile [d][k]
  __shared__ unsigned short hts[64*136];  // h^T tile [c][k], rows 272B (16B-aligned)
  __shared__ unsigned int pb[64*65];      // p as bf16 pairs, 65-u32 rows (2-way max)
  __shared__ float gs[64*8];
  __shared__ float alpha_s[64];
  __shared__ float l_s[64];

  const int t  = threadIdx.x;
  const int qt = blockIdx.x;
  const int b  = blockIdx.y;
  const int q0 = qt * 64;

  if (t < 128) {
    float4 v = ((const float4*)(g_g + ((long)b*4096 + q0)*8))[t];
    *(float4*)&gs[t*4] = v;
  }
  __syncthreads();

  const int sq  = t >> 2;   // softmax row 0..63
  const int skg = t & 3;    // key sub-group (quad lanes share a row)
  float greg[8];
  #pragma unroll
  for (int d = 0; d < 8; ++d) greg[d] = gs[sq*8 + d];

  const int lane = t & 63;
  const int wv   = t >> 6;
  const int l15  = lane & 15;
  const int quad = lane >> 4;

  float m_run = -1e30f;
  float l_run = 0.f;
  f32x4 acc[4] = {};   // O rows (16wv+quad*4+r) x cols (cf*16+l15), C-layout

  const float* ftg_b = ft_g + (long)b*8*4096;
  const unsigned short* htg_b = ht_g + (long)b*64*4096;

  for (int kt = 0; kt < 32; ++kt) {
    const int j0 = kt * 128;
    __syncthreads();  // prev phase B done before restaging
    {
      int d = t >> 5, i = (t & 31) * 4;
      float4 v = *(const float4*)(ftg_b + (long)d*4096 + j0 + i);
      *(float4*)&fts[d*128 + i] = v;
    }
    {
      int c = t >> 2, seg = t & 3;
      const unsigned short* src = htg_b + (long)c*4096 + j0 + seg*32;
      #pragma unroll
      for (int uu = 0; uu < 4; ++uu) {
        uint4 v = *(const uint4*)(src + uu*8);
        *(uint4*)&hts[c*136 + seg*32 + uu*8] = v;
      }
    }
    __syncthreads();

    // ---- Phase A: scores (fp32 VALU, dot-8) ----
    float s[4][8];
    #pragma unroll
    for (int ig = 0; ig < 4; ++ig)
      #pragma unroll
      for (int j = 0; j < 8; ++j) s[ig][j] = 0.f;

    #pragma unroll
    for (int d = 0; d < 8; ++d) {
      const float gd = greg[d];
      #pragma unroll
      for (int ig = 0; ig < 4; ++ig) {
        float4 v0 = *(const float4*)&fts[d*128 + ig*32 + skg*8];
        float4 v1 = *(const float4*)&fts[d*128 + ig*32 + skg*8 + 4];
        s[ig][0] = fmaf(gd, v0.x, s[ig][0]);
        s[ig][1] = fmaf(gd, v0.y, s[ig][1]);
        s[ig][2] = fmaf(gd, v0.z, s[ig][2]);
        s[ig][3] = fmaf(gd, v0.w, s[ig][3]);
        s[ig][4] = fmaf(gd, v1.x, s[ig][4]);
        s[ig][5] = fmaf(gd, v1.y, s[ig][5]);
        s[ig][6] = fmaf(gd, v1.z, s[ig][6]);
        s[ig][7] = fmaf(gd, v1.w, s[ig][7]);
      }
    }

    // ---- online softmax (row = 4 quad lanes) ----
    float mx = -1e30f;
    #pragma unroll
    for (int ig = 0; ig < 4; ++ig)
      #pragma unroll
      for (int j = 0; j < 8; ++j) mx = fmaxf(mx, s[ig][j]);
    mx = fmaxf(mx, __shfl_xor(mx, 1));
    mx = fmaxf(mx, __shfl_xor(mx, 2));
    const float m_new = fmaxf(m_run, mx);
    const float alpha = __expf(m_run - m_new);
    float sum = 0.f;
    #pragma unroll
    for (int ig = 0; ig < 4; ++ig)
      #pragma unroll
      for (int j = 0; j < 8; ++j) {
        float p = __expf(s[ig][j] - m_new);
        s[ig][j] = p;
        sum += p;
      }
    sum += __shfl_xor(sum, 1);
    sum += __shfl_xor(sum, 2);
    l_run = l_run * alpha + sum;
    m_run = m_new;
    if (skg == 0) alpha_s[sq] = alpha;

    // p -> bf16 pairs; pair index (k>>1) = ig*16 + skg*4 + jj
    #pragma unroll
    for (int ig = 0; ig < 4; ++ig)
      #pragma unroll
      for (int jj = 0; jj < 4; ++jj)
        pb[sq*65 + ig*16 + skg*4 + jj] = pack_bf16_pair(s[ig][2*jj], s[ig][2*jj+1]);

    __syncthreads();

    // ---- Phase B: rescale + MFMA P(16x128) @ H(128x64) per wave ----
    const f32x4 avv = *(const f32x4*)&alpha_s[wv*16 + quad*4];
    #pragma unroll
    for (int cf = 0; cf < 4; ++cf) acc[cf] *= avv;

    #pragma unroll
    for (int kk = 0; kk < 4; ++kk) {
      union { unsigned int u[4]; bf16x8 v; } au;
      #pragma unroll
      for (int jj = 0; jj < 4; ++jj)
        au.u[jj] = pb[(wv*16 + l15)*65 + kk*16 + quad*4 + jj];
      const bf16x8 af = au.v;  // A[m=l15][k=quad*8+j]
      #pragma unroll
      for (int cf = 0; cf < 4; ++cf) {
        const bf16x8 bfv = *(const bf16x8*)&hts[(cf*16 + l15)*136 + kk*32 + quad*8];
        acc[cf] = __builtin_amdgcn_mfma_f32_16x16x32_bf16(af, bfv, acc[cf], 0, 0, 0);
      }
    }
  }

  if (skg == 0) l_s[sq] = l_run;
  __syncthreads();

  const f32x4 lvv = *(const f32x4*)&l_s[wv*16 + quad*4];
  float inv[4];
  #pragma unroll
  for (int rr = 0; rr < 4; ++rr) inv[rr] = 1.0f / lvv[rr];
  const float gma = gamma_p[0];

  #pragma unroll
  for (int cf = 0; cf < 4; ++cf) {
    #pragma unroll
    for (int rr = 0; rr < 4; ++rr) {
      const int row = wv*16 + quad*4 + rr;
      const long n = q0 + row;
      const long idx = (((long)b*4096 + n)*64) + cf*16 + l15;
      out[idx] = fmaf(gma, acc[cf][rr] * inv[rr], x[idx]);
    }
  }
}

extern "C" void kernel_launch(void* const* d_in, const int* in_sizes, int n_in,
                              void* d_out, int out_size, void* d_ws, size_t ws_size,
                              hipStream_t stream) {
  const float* x  = (const float*)d_in[0];
  const float* kf = (const float*)d_in[1];
  const float* kg = (const float*)d_in[2];
  const float* kh = (const float*)d_in[3];
  const float* gamma = (const float*)d_in[4];
  float* out = (float*)d_out;

  char* ws = (char*)d_ws;
  float* g_g  = (float*)ws;                          // 8*4096*8*4  = 1 MB
  float* ft_g = (float*)(ws + (1l << 20));           // 8*8*4096*4  = 1 MB
  unsigned short* ht_g = (unsigned short*)(ws + (2l << 20)); // 8*64*4096*2 = 4 MB

  proj_kernel<<<512, 256, 0, stream>>>(x, kf, kg, kh, g_g, ft_g, ht_g);
  attn_kernel<<<dim3(64, 8), 256, 0, stream>>>(x, g_g, ft_g, ht_g, gamma, out);
}